// Round 1
// baseline (132.556 us; speedup 1.0000x reference)
//
#include <hip/hip_runtime.h>
#include <math.h>

#define BB 2
#define LL 2048
#define DM 512
#define DS 16
#define DTR 32
#define KK 64          // DTR + 2*DS
#define NC 32          // chunks
#define CL 64          // LL / NC
#define NROWS (BB * LL)

// ws layout (floats)
#define OFF_WXT  0                       // 512*64   = 32768
#define OFF_WDTT (OFF_WXT + DM * KK)     // 32*512   = 16384
#define OFF_XZ   (OFF_WDTT + DTR * DM)   // 4096*64  = 262144
#define OFF_DT   (OFF_XZ + NROWS * KK)   // 4096*512 = 2097152
#define OFF_P    (OFF_DT + NROWS * DM)   // 32*16384 = 524288
#define OFF_H    (OFF_P + NC * BB * DM * DS)

__global__ __launch_bounds__(256) void k_transpose(const float* __restrict__ W_x,
                                                   const float* __restrict__ W_dt,
                                                   float* __restrict__ WxT,
                                                   float* __restrict__ WdtT) {
  int i = blockIdx.x * 256 + threadIdx.x;
  if (i < DM * KK) {                 // WxT[d][k] = W_x[k][d]
    int d = i / KK, k = i % KK;
    WxT[i] = W_x[k * DM + d];
  }
  int j = i - DM * KK;
  if (j >= 0 && j < DTR * DM) {      // WdtT[r][d] = W_dt[d][r]
    int r = j / DM, d = j % DM;
    WdtT[j] = W_dt[d * DTR + r];
  }
}

// xz[row][k] = sum_d x[row][d] * W_x[k][d]; one wave = 64 k, 4 rows
__global__ __launch_bounds__(256) void k_xz(const float* __restrict__ x,
                                            const float* __restrict__ WxT,
                                            float* __restrict__ xz) {
  int k = threadIdx.x & 63;
  int wave = threadIdx.x >> 6;
  int row0 = blockIdx.x * 16 + wave * 4;
  const float* x0 = x + (size_t)row0 * DM;
  float acc0 = 0.f, acc1 = 0.f, acc2 = 0.f, acc3 = 0.f;
#pragma unroll 4
  for (int d = 0; d < DM; ++d) {
    float w = WxT[d * KK + k];
    acc0 += x0[d] * w;
    acc1 += x0[DM + d] * w;
    acc2 += x0[2 * DM + d] * w;
    acc3 += x0[3 * DM + d] * w;
  }
  float* o = xz + (size_t)row0 * KK + k;
  o[0] = acc0; o[KK] = acc1; o[2 * KK] = acc2; o[3 * KK] = acc3;
}

// dt[row][d] = clip(softplus(sum_r dt_raw[row][r]*W_dt[d][r] + b_dt[d]), 1e-4, 10)
__global__ __launch_bounds__(256) void k_dt(const float* __restrict__ xz,
                                            const float* __restrict__ WdtT,
                                            const float* __restrict__ b_dt,
                                            float* __restrict__ dtw) {
  int d = (blockIdx.x & 1) * 256 + threadIdx.x;
  int row0 = (blockIdx.x >> 1) * 8;
  float acc[8] = {0, 0, 0, 0, 0, 0, 0, 0};
  for (int r = 0; r < DTR; ++r) {
    float w = WdtT[r * DM + d];
#pragma unroll
    for (int i = 0; i < 8; ++i)
      acc[i] += xz[(row0 + i) * KK + r] * w;
  }
  float bd = b_dt[d];
#pragma unroll
  for (int i = 0; i < 8; ++i) {
    float v = acc[i] + bd;
    float sp = v > 20.f ? v : log1pf(expf(v));
    sp = fminf(fmaxf(sp, 1e-4f), 10.f);
    dtw[(size_t)(row0 + i) * DM + d] = sp;
  }
}

// Pass 1: per-chunk summaries. tid = dloc*16 + s. chain = base + tid.
__global__ __launch_bounds__(256) void k_scan1(const float* __restrict__ x,
                                               const float* __restrict__ xz,
                                               const float* __restrict__ dtw,
                                               const float* __restrict__ A_log,
                                               float* __restrict__ Pb,
                                               float* __restrict__ Hb) {
  int c = blockIdx.x;
  int b = blockIdx.y >> 5;
  int dblk = blockIdx.y & 31;
  int tid = threadIdx.x;
  int s = tid & 15, dloc = tid >> 4;
  int d = dblk * 16 + dloc;
  float A = fminf(-expf(A_log[d * DS + s]), -1e-4f);
  float P = 1.f, H = 0.f;
  int l0 = c * CL;
  const float* dt_p = dtw + (size_t)b * LL * DM + d;
  const float* x_p  = x   + (size_t)b * LL * DM + d;
  const float* B_p  = xz  + (size_t)b * LL * KK + DTR + s;
  for (int l = l0; l < l0 + CL; ++l) {
    float dtv = dt_p[(size_t)l * DM];
    float xv  = x_p[(size_t)l * DM];
    float Bv  = B_p[(size_t)l * KK];
    float ab = fminf(expf(dtv * A), 1.f);
    H = ab * H + dtv * Bv * xv;
    P *= ab;
  }
  int base = b * (DM * DS) + dblk * 256;
  Pb[c * (BB * DM * DS) + base + tid] = P;
  Hb[c * (BB * DM * DS) + base + tid] = H;
}

// Pass 2: carry prologue + local scan + y
__global__ __launch_bounds__(256) void k_scan2(const float* __restrict__ x,
                                               const float* __restrict__ xz,
                                               const float* __restrict__ dtw,
                                               const float* __restrict__ A_log,
                                               const float* __restrict__ Dv,
                                               const float* __restrict__ Pb,
                                               const float* __restrict__ Hb,
                                               float* __restrict__ y) {
  int c = blockIdx.x;
  int b = blockIdx.y >> 5;
  int dblk = blockIdx.y & 31;
  int tid = threadIdx.x;
  int s = tid & 15, dloc = tid >> 4;
  int d = dblk * 16 + dloc;
  int base = b * (DM * DS) + dblk * 256;

  float h = 0.f;
  for (int cc = 0; cc < c; ++cc) {
    float P = Pb[cc * (BB * DM * DS) + base + tid];
    float H = Hb[cc * (BB * DM * DS) + base + tid];
    h = P * h + H;
  }

  float A = fminf(-expf(A_log[d * DS + s]), -1e-4f);
  float Dd = Dv[d];
  int l0 = c * CL;
  const float* dt_p = dtw + (size_t)b * LL * DM + d;
  const float* x_p  = x   + (size_t)b * LL * DM + d;
  const float* B_p  = xz  + (size_t)b * LL * KK + DTR + s;
  const float* C_p  = xz  + (size_t)b * LL * KK + DTR + DS + s;
  for (int l = l0; l < l0 + CL; ++l) {
    float dtv = dt_p[(size_t)l * DM];
    float xv  = x_p[(size_t)l * DM];
    float Bv  = B_p[(size_t)l * KK];
    float Cv  = C_p[(size_t)l * KK];
    float ab = fminf(expf(dtv * A), 1.f);
    h = ab * h + dtv * Bv * xv;
    float p = h * Cv;
    p += __shfl_xor(p, 1);
    p += __shfl_xor(p, 2);
    p += __shfl_xor(p, 4);
    p += __shfl_xor(p, 8);
    if (s == 0)
      y[((size_t)b * LL + l) * DM + d] = p + xv * Dd;
  }
}

extern "C" void kernel_launch(void* const* d_in, const int* in_sizes, int n_in,
                              void* d_out, int out_size, void* d_ws, size_t ws_size,
                              hipStream_t stream) {
  const float* x     = (const float*)d_in[0];
  const float* W_x   = (const float*)d_in[1];
  const float* W_dt  = (const float*)d_in[2];
  const float* b_dt  = (const float*)d_in[3];
  const float* A_log = (const float*)d_in[4];
  const float* Dv    = (const float*)d_in[5];
  float* y = (float*)d_out;

  float* ws   = (float*)d_ws;
  float* WxT  = ws + OFF_WXT;
  float* WdtT = ws + OFF_WDTT;
  float* xz   = ws + OFF_XZ;
  float* dtw  = ws + OFF_DT;
  float* Pb   = ws + OFF_P;
  float* Hb   = ws + OFF_H;

  k_transpose<<<192, 256, 0, stream>>>(W_x, W_dt, WxT, WdtT);
  k_xz<<<NROWS / 16, 256, 0, stream>>>(x, WxT, xz);
  k_dt<<<(NROWS / 8) * 2, 256, 0, stream>>>(xz, WdtT, b_dt, dtw);
  dim3 g(NC, BB * (DM / 16));
  k_scan1<<<g, 256, 0, stream>>>(x, xz, dtw, A_log, Pb, Hb);
  k_scan2<<<g, 256, 0, stream>>>(x, xz, dtw, A_log, Dv, Pb, Hb, y);
}

// Round 3
// 108.743 us; speedup vs baseline: 1.2190x; 1.2190x over previous
//
#include <hip/hip_runtime.h>
#include <math.h>

#define BB 2
#define LL 2048
#define DM 512
#define DS 16
#define DTR 32
#define KK 64          // DTR + 2*DS
#define NC 32          // chunks
#define CL 64          // LL / NC
#define NROWS (BB * LL)
#define CHAINS (BB * DM * DS)   // 16384

// ws layout (floats) — total 3,457,024 floats = 13.8 MB (same as round 1, which passed)
#define OFF_WXT  0                       // 512*64   = 32768
#define OFF_WDTT (OFF_WXT + DM * KK)     // 32*512   = 16384
#define OFF_XZ   (OFF_WDTT + DTR * DM)   // 4096*64  = 262144
#define OFF_DT   (OFF_XZ + NROWS * KK)   // 4096*512 = 2097152
#define OFF_P    (OFF_DT + NROWS * DM)   // 32*16384 = 524288
#define OFF_H    (OFF_P + NC * CHAINS)   // 32*16384 = 524288

__global__ __launch_bounds__(256) void k_transpose(const float* __restrict__ W_x,
                                                   const float* __restrict__ W_dt,
                                                   float* __restrict__ WxT,
                                                   float* __restrict__ WdtT) {
  int i = blockIdx.x * 256 + threadIdx.x;
  if (i < DM * KK) {                 // WxT[d][k] = W_x[k][d]
    int d = i / KK, k = i % KK;
    WxT[i] = W_x[k * DM + d];
  }
  int j = i - DM * KK;
  if (j >= 0 && j < DTR * DM) {      // WdtT[r][d] = W_dt[d][r]
    int r = j / DM, d = j % DM;
    WdtT[j] = W_dt[d * DTR + r];
  }
}

// xz[row][k] = sum_d x[row][d] * W_x[k][d]
// 2 rows per wave, 4 waves/block -> 8 rows/block, 512 blocks = 2048 waves (2/SIMD)
__global__ __launch_bounds__(256) void k_xz(const float* __restrict__ x,
                                            const float* __restrict__ WxT,
                                            float* __restrict__ xz) {
  int k = threadIdx.x & 63;
  int wv = threadIdx.x >> 6;
  int row0 = blockIdx.x * 8 + wv * 2;
  const float* xr0 = x + (size_t)row0 * DM;
  const float* xr1 = xr0 + DM;
  float acc0 = 0.f, acc1 = 0.f;
  for (int d = 0; d < DM; d += 8) {
    float4 u0 = *(const float4*)(xr0 + d);
    float4 u1 = *(const float4*)(xr0 + d + 4);
    float4 v0 = *(const float4*)(xr1 + d);
    float4 v1 = *(const float4*)(xr1 + d + 4);
    float w0 = WxT[(d + 0) * KK + k];
    float w1 = WxT[(d + 1) * KK + k];
    float w2 = WxT[(d + 2) * KK + k];
    float w3 = WxT[(d + 3) * KK + k];
    float w4 = WxT[(d + 4) * KK + k];
    float w5 = WxT[(d + 5) * KK + k];
    float w6 = WxT[(d + 6) * KK + k];
    float w7 = WxT[(d + 7) * KK + k];
    acc0 = fmaf(u0.x, w0, acc0); acc1 = fmaf(v0.x, w0, acc1);
    acc0 = fmaf(u0.y, w1, acc0); acc1 = fmaf(v0.y, w1, acc1);
    acc0 = fmaf(u0.z, w2, acc0); acc1 = fmaf(v0.z, w2, acc1);
    acc0 = fmaf(u0.w, w3, acc0); acc1 = fmaf(v0.w, w3, acc1);
    acc0 = fmaf(u1.x, w4, acc0); acc1 = fmaf(v1.x, w4, acc1);
    acc0 = fmaf(u1.y, w5, acc0); acc1 = fmaf(v1.y, w5, acc1);
    acc0 = fmaf(u1.z, w6, acc0); acc1 = fmaf(v1.z, w6, acc1);
    acc0 = fmaf(u1.w, w7, acc0); acc1 = fmaf(v1.w, w7, acc1);
  }
  xz[(size_t)row0 * KK + k] = acc0;
  xz[(size_t)(row0 + 1) * KK + k] = acc1;
}

// dt[row][d] = clip(softplus(sum_r dt_raw[row][r]*W_dt[d][r] + b_dt[d]), 1e-4, 10)
__global__ __launch_bounds__(256) void k_dt(const float* __restrict__ xz,
                                            const float* __restrict__ WdtT,
                                            const float* __restrict__ b_dt,
                                            float* __restrict__ dtw) {
  int d = (blockIdx.x & 1) * 256 + threadIdx.x;
  int row0 = (blockIdx.x >> 1) * 8;
  float acc[8] = {0, 0, 0, 0, 0, 0, 0, 0};
  for (int r = 0; r < DTR; ++r) {
    float w = WdtT[r * DM + d];
#pragma unroll
    for (int i = 0; i < 8; ++i)
      acc[i] += xz[(row0 + i) * KK + r] * w;
  }
  float bd = b_dt[d];
#pragma unroll
  for (int i = 0; i < 8; ++i) {
    float v = acc[i] + bd;
    float sp = v > 20.f ? v : log1pf(expf(v));
    sp = fminf(fmaxf(sp, 1e-4f), 10.f);
    dtw[(size_t)(row0 + i) * DM + d] = sp;
  }
}

// Pass 1: per-chunk (prod A_bar, local h) summaries. 4 states per thread.
// tid: s4 = tid&3 (owns s in [4*s4, 4*s4+4)), dloc = tid>>2 (64 d per block).
// grid: (NC, BB*8)  — blockIdx.y: b = y>>3, dblk = y&7.
__global__ __launch_bounds__(256) void k_scan1(const float* __restrict__ x,
                                               const float* __restrict__ xz,
                                               const float* __restrict__ dtw,
                                               const float* __restrict__ A_log,
                                               float* __restrict__ Pb,
                                               float* __restrict__ Hb) {
  int c = blockIdx.x;
  int b = blockIdx.y >> 3;
  int dblk = blockIdx.y & 7;
  int tid = threadIdx.x;
  int s4 = tid & 3, dloc = tid >> 2;
  int d = dblk * 64 + dloc;

  float4 al = *(const float4*)(A_log + d * DS + s4 * 4);
  float A0 = fminf(-expf(al.x), -1e-4f);
  float A1 = fminf(-expf(al.y), -1e-4f);
  float A2 = fminf(-expf(al.z), -1e-4f);
  float A3 = fminf(-expf(al.w), -1e-4f);

  float P0 = 1.f, P1 = 1.f, P2 = 1.f, P3 = 1.f;
  float h0 = 0.f, h1 = 0.f, h2 = 0.f, h3 = 0.f;

  int l0 = c * CL;
  const float* dt_p = dtw + ((size_t)b * LL + l0) * DM + d;
  const float* x_p  = x   + ((size_t)b * LL + l0) * DM + d;
  const float* B_p  = xz  + ((size_t)b * LL + l0) * KK + DTR + s4 * 4;
#pragma unroll 4
  for (int l = 0; l < CL; ++l) {
    float dtv = dt_p[(size_t)l * DM];
    float xv  = x_p[(size_t)l * DM];
    float4 Bv = *(const float4*)(B_p + (size_t)l * KK);
    float dtx = dtv * xv;
    float a0 = fminf(__expf(dtv * A0), 1.f);
    float a1 = fminf(__expf(dtv * A1), 1.f);
    float a2 = fminf(__expf(dtv * A2), 1.f);
    float a3 = fminf(__expf(dtv * A3), 1.f);
    h0 = fmaf(a0, h0, dtx * Bv.x); P0 *= a0;
    h1 = fmaf(a1, h1, dtx * Bv.y); P1 *= a1;
    h2 = fmaf(a2, h2, dtx * Bv.z); P2 *= a2;
    h3 = fmaf(a3, h3, dtx * Bv.w); P3 *= a3;
  }
  int chain0 = (b * DM + d) * DS + s4 * 4;
  *(float4*)(Pb + (size_t)c * CHAINS + chain0) = make_float4(P0, P1, P2, P3);
  *(float4*)(Hb + (size_t)c * CHAINS + chain0) = make_float4(h0, h1, h2, h3);
}

// Pass 2: carry prologue (pure reads of Pb/Hb) + local scan + y output.
__global__ __launch_bounds__(256) void k_scan2(const float* __restrict__ x,
                                               const float* __restrict__ xz,
                                               const float* __restrict__ dtw,
                                               const float* __restrict__ A_log,
                                               const float* __restrict__ Dv,
                                               const float* __restrict__ Pb,
                                               const float* __restrict__ Hb,
                                               float* __restrict__ y) {
  int c = blockIdx.x;
  int b = blockIdx.y >> 3;
  int dblk = blockIdx.y & 7;
  int tid = threadIdx.x;
  int s4 = tid & 3, dloc = tid >> 2;
  int d = dblk * 64 + dloc;

  int chain0 = (b * DM + d) * DS + s4 * 4;
  float h0 = 0.f, h1 = 0.f, h2 = 0.f, h3 = 0.f;
  for (int cc = 0; cc < c; ++cc) {
    float4 Pv = *(const float4*)(Pb + (size_t)cc * CHAINS + chain0);
    float4 Hv = *(const float4*)(Hb + (size_t)cc * CHAINS + chain0);
    h0 = fmaf(Pv.x, h0, Hv.x);
    h1 = fmaf(Pv.y, h1, Hv.y);
    h2 = fmaf(Pv.z, h2, Hv.z);
    h3 = fmaf(Pv.w, h3, Hv.w);
  }

  float4 al = *(const float4*)(A_log + d * DS + s4 * 4);
  float A0 = fminf(-expf(al.x), -1e-4f);
  float A1 = fminf(-expf(al.y), -1e-4f);
  float A2 = fminf(-expf(al.z), -1e-4f);
  float A3 = fminf(-expf(al.w), -1e-4f);
  float Dd = Dv[d];

  int l0 = c * CL;
  const float* dt_p = dtw + ((size_t)b * LL + l0) * DM + d;
  const float* x_p  = x   + ((size_t)b * LL + l0) * DM + d;
  const float* B_p  = xz  + ((size_t)b * LL + l0) * KK + DTR + s4 * 4;
  const float* C_p  = B_p + DS;
  float* y_p = y + ((size_t)b * LL + l0) * DM + d;
#pragma unroll 4
  for (int l = 0; l < CL; ++l) {
    float dtv = dt_p[(size_t)l * DM];
    float xv  = x_p[(size_t)l * DM];
    float4 Bv = *(const float4*)(B_p + (size_t)l * KK);
    float4 Cv = *(const float4*)(C_p + (size_t)l * KK);
    float dtx = dtv * xv;
    float a0 = fminf(__expf(dtv * A0), 1.f);
    float a1 = fminf(__expf(dtv * A1), 1.f);
    float a2 = fminf(__expf(dtv * A2), 1.f);
    float a3 = fminf(__expf(dtv * A3), 1.f);
    h0 = fmaf(a0, h0, dtx * Bv.x);
    h1 = fmaf(a1, h1, dtx * Bv.y);
    h2 = fmaf(a2, h2, dtx * Bv.z);
    h3 = fmaf(a3, h3, dtx * Bv.w);
    float p = h0 * Cv.x;
    p = fmaf(h1, Cv.y, p);
    p = fmaf(h2, Cv.z, p);
    p = fmaf(h3, Cv.w, p);
    p += __shfl_xor(p, 1);
    p += __shfl_xor(p, 2);
    if (s4 == 0)
      y_p[(size_t)l * DM] = fmaf(xv, Dd, p);
  }
}

extern "C" void kernel_launch(void* const* d_in, const int* in_sizes, int n_in,
                              void* d_out, int out_size, void* d_ws, size_t ws_size,
                              hipStream_t stream) {
  const float* x     = (const float*)d_in[0];
  const float* W_x   = (const float*)d_in[1];
  const float* W_dt  = (const float*)d_in[2];
  const float* b_dt  = (const float*)d_in[3];
  const float* A_log = (const float*)d_in[4];
  const float* Dv    = (const float*)d_in[5];
  float* y = (float*)d_out;

  float* ws   = (float*)d_ws;
  float* WxT  = ws + OFF_WXT;
  float* WdtT = ws + OFF_WDTT;
  float* xz   = ws + OFF_XZ;
  float* dtw  = ws + OFF_DT;
  float* Pb   = ws + OFF_P;
  float* Hb   = ws + OFF_H;

  k_transpose<<<192, 256, 0, stream>>>(W_x, W_dt, WxT, WdtT);
  k_xz<<<NROWS / 8, 256, 0, stream>>>(x, WxT, xz);
  k_dt<<<(NROWS / 8) * 2, 256, 0, stream>>>(xz, WdtT, b_dt, dtw);
  dim3 g(NC, BB * (DM / 64));
  k_scan1<<<g, 256, 0, stream>>>(x, xz, dtw, A_log, Pb, Hb);
  k_scan2<<<g, 256, 0, stream>>>(x, xz, dtw, A_log, Dv, Pb, Hb, y);
}

// Round 4
// 89.873 us; speedup vs baseline: 1.4749x; 1.2100x over previous
//
#include <hip/hip_runtime.h>
#include <math.h>

#define BB 2
#define LL 2048
#define DM 512
#define DS 16
#define DTR 32
#define KK 64          // DTR + 2*DS
#define NC 128         // chunks
#define CL 16          // LL / NC
#define NROWS (BB * LL)
#define CHAINS (BB * DM * DS)   // 16384

// ws layout (floats) — total 8,699,904 floats = 34.8 MB
#define OFF_WXT  0                        // 512*64    = 32768
#define OFF_WDTT (OFF_WXT + DM * KK)      // 32*512    = 16384
#define OFF_XZ   (OFF_WDTT + DTR * DM)    // 4096*64   = 262144
#define OFF_DT   (OFF_XZ + NROWS * KK)    // 4096*512  = 2097152
#define OFF_P    (OFF_DT + NROWS * DM)    // 128*16384 = 2097152
#define OFF_H    (OFF_P + NC * CHAINS)    // 128*16384 = 2097152
#define OFF_C    (OFF_H + NC * CHAINS)    // 128*16384 = 2097152

__global__ __launch_bounds__(256) void k_transpose(const float* __restrict__ W_x,
                                                   const float* __restrict__ W_dt,
                                                   float* __restrict__ WxT,
                                                   float* __restrict__ WdtT) {
  int i = blockIdx.x * 256 + threadIdx.x;
  if (i < DM * KK) {                 // WxT[d][k] = W_x[k][d]
    int d = i / KK, k = i % KK;
    WxT[i] = W_x[k * DM + d];
  }
  int j = i - DM * KK;
  if (j >= 0 && j < DTR * DM) {      // WdtT[r][d] = W_dt[d][r]
    int r = j / DM, d = j % DM;
    WdtT[j] = W_dt[d * DTR + r];
  }
}

// xz[row][k] = sum_d x[row][d] * W_x[k][d]
// 512-thread block: 8 waves = 4 row-pairs x 2 d-halves; LDS reduce across halves.
// 512 blocks -> 4096 waves (16/CU), per-wave K-chain halved.
__global__ __launch_bounds__(512) void k_xz(const float* __restrict__ x,
                                            const float* __restrict__ WxT,
                                            float* __restrict__ xz) {
  __shared__ float red[4][2][64];
  int k = threadIdx.x & 63;
  int wv = threadIdx.x >> 6;   // 0..7
  int rp = wv & 3;             // row pair
  int dh = wv >> 2;            // d half
  int row0 = blockIdx.x * 8 + rp * 2;
  const float* xr0 = x + (size_t)row0 * DM + dh * (DM / 2);
  const float* xr1 = xr0 + DM;
  const float* Wp = WxT + (size_t)dh * (DM / 2) * KK;
  float acc0 = 0.f, acc1 = 0.f;
  for (int d = 0; d < DM / 2; d += 8) {
    float4 u0 = *(const float4*)(xr0 + d);
    float4 u1 = *(const float4*)(xr0 + d + 4);
    float4 v0 = *(const float4*)(xr1 + d);
    float4 v1 = *(const float4*)(xr1 + d + 4);
    float w0 = Wp[(d + 0) * KK + k];
    float w1 = Wp[(d + 1) * KK + k];
    float w2 = Wp[(d + 2) * KK + k];
    float w3 = Wp[(d + 3) * KK + k];
    float w4 = Wp[(d + 4) * KK + k];
    float w5 = Wp[(d + 5) * KK + k];
    float w6 = Wp[(d + 6) * KK + k];
    float w7 = Wp[(d + 7) * KK + k];
    acc0 = fmaf(u0.x, w0, acc0); acc1 = fmaf(v0.x, w0, acc1);
    acc0 = fmaf(u0.y, w1, acc0); acc1 = fmaf(v0.y, w1, acc1);
    acc0 = fmaf(u0.z, w2, acc0); acc1 = fmaf(v0.z, w2, acc1);
    acc0 = fmaf(u0.w, w3, acc0); acc1 = fmaf(v0.w, w3, acc1);
    acc0 = fmaf(u1.x, w4, acc0); acc1 = fmaf(v1.x, w4, acc1);
    acc0 = fmaf(u1.y, w5, acc0); acc1 = fmaf(v1.y, w5, acc1);
    acc0 = fmaf(u1.z, w6, acc0); acc1 = fmaf(v1.z, w6, acc1);
    acc0 = fmaf(u1.w, w7, acc0); acc1 = fmaf(v1.w, w7, acc1);
  }
  if (dh == 1) {
    red[rp][0][k] = acc0;
    red[rp][1][k] = acc1;
  }
  __syncthreads();
  if (dh == 0) {
    acc0 += red[rp][0][k];
    acc1 += red[rp][1][k];
    xz[(size_t)row0 * KK + k] = acc0;
    xz[(size_t)(row0 + 1) * KK + k] = acc1;
  }
}

// dt[row][d] = clip(softplus(sum_r dt_raw[row][r]*W_dt[d][r] + b_dt[d]), 1e-4, 10)
__global__ __launch_bounds__(256) void k_dt(const float* __restrict__ xz,
                                            const float* __restrict__ WdtT,
                                            const float* __restrict__ b_dt,
                                            float* __restrict__ dtw) {
  int d = (blockIdx.x & 1) * 256 + threadIdx.x;
  int row0 = (blockIdx.x >> 1) * 8;
  float acc[8] = {0, 0, 0, 0, 0, 0, 0, 0};
  for (int r = 0; r < DTR; ++r) {
    float w = WdtT[r * DM + d];
#pragma unroll
    for (int i = 0; i < 8; ++i)
      acc[i] += xz[(row0 + i) * KK + r] * w;
  }
  float bd = b_dt[d];
#pragma unroll
  for (int i = 0; i < 8; ++i) {
    float v = acc[i] + bd;
    float sp = v > 20.f ? v : log1pf(expf(v));
    sp = fminf(fmaxf(sp, 1e-4f), 10.f);
    dtw[(size_t)(row0 + i) * DM + d] = sp;
  }
}

// Pass 1: per-chunk (prod A_bar, local h). 4 states/thread.
// grid (NC, BB*8): b = y>>3, dblk = y&7. tid: s4=tid&3, dloc=tid>>2.
__global__ __launch_bounds__(256) void k_scan1(const float* __restrict__ x,
                                               const float* __restrict__ xz,
                                               const float* __restrict__ dtw,
                                               const float* __restrict__ A_log,
                                               float* __restrict__ Pb,
                                               float* __restrict__ Hb) {
  int c = blockIdx.x;
  int b = blockIdx.y >> 3;
  int dblk = blockIdx.y & 7;
  int tid = threadIdx.x;
  int s4 = tid & 3, dloc = tid >> 2;
  int d = dblk * 64 + dloc;

  float4 al = *(const float4*)(A_log + d * DS + s4 * 4);
  float A0 = fminf(-expf(al.x), -1e-4f);
  float A1 = fminf(-expf(al.y), -1e-4f);
  float A2 = fminf(-expf(al.z), -1e-4f);
  float A3 = fminf(-expf(al.w), -1e-4f);

  float P0 = 1.f, P1 = 1.f, P2 = 1.f, P3 = 1.f;
  float h0 = 0.f, h1 = 0.f, h2 = 0.f, h3 = 0.f;

  int l0 = c * CL;
  const float* dt_p = dtw + ((size_t)b * LL + l0) * DM + d;
  const float* x_p  = x   + ((size_t)b * LL + l0) * DM + d;
  const float* B_p  = xz  + ((size_t)b * LL + l0) * KK + DTR + s4 * 4;
#pragma unroll 4
  for (int l = 0; l < CL; ++l) {
    float dtv = dt_p[(size_t)l * DM];
    float xv  = x_p[(size_t)l * DM];
    float4 Bv = *(const float4*)(B_p + (size_t)l * KK);
    float dtx = dtv * xv;
    float a0 = fminf(__expf(dtv * A0), 1.f);
    float a1 = fminf(__expf(dtv * A1), 1.f);
    float a2 = fminf(__expf(dtv * A2), 1.f);
    float a3 = fminf(__expf(dtv * A3), 1.f);
    h0 = fmaf(a0, h0, dtx * Bv.x); P0 *= a0;
    h1 = fmaf(a1, h1, dtx * Bv.y); P1 *= a1;
    h2 = fmaf(a2, h2, dtx * Bv.z); P2 *= a2;
    h3 = fmaf(a3, h3, dtx * Bv.w); P3 *= a3;
  }
  int chain0 = (b * DM + d) * DS + s4 * 4;
  *(float4*)(Pb + (size_t)c * CHAINS + chain0) = make_float4(P0, P1, P2, P3);
  *(float4*)(Hb + (size_t)c * CHAINS + chain0) = make_float4(h0, h1, h2, h3);
}

// Carry scan over chunks. PURE: reads Pb/Hb, writes Cb (carry-in per chunk).
// One thread per chain; all loads/stores coalesced.
__global__ __launch_bounds__(256) void k_mid(const float* __restrict__ Pb,
                                             const float* __restrict__ Hb,
                                             float* __restrict__ Cb) {
  int chain = blockIdx.x * 256 + threadIdx.x;
  float h = 0.f;
#pragma unroll 8
  for (int c = 0; c < NC; ++c) {
    float Pv = Pb[(size_t)c * CHAINS + chain];
    float Hv = Hb[(size_t)c * CHAINS + chain];
    Cb[(size_t)c * CHAINS + chain] = h;
    h = fmaf(Pv, h, Hv);
  }
}

// Pass 2: carry-in (one float4) + local scan + y output.
__global__ __launch_bounds__(256) void k_scan2(const float* __restrict__ x,
                                               const float* __restrict__ xz,
                                               const float* __restrict__ dtw,
                                               const float* __restrict__ A_log,
                                               const float* __restrict__ Dv,
                                               const float* __restrict__ Cb,
                                               float* __restrict__ y) {
  int c = blockIdx.x;
  int b = blockIdx.y >> 3;
  int dblk = blockIdx.y & 7;
  int tid = threadIdx.x;
  int s4 = tid & 3, dloc = tid >> 2;
  int d = dblk * 64 + dloc;

  int chain0 = (b * DM + d) * DS + s4 * 4;
  float4 hc = *(const float4*)(Cb + (size_t)c * CHAINS + chain0);
  float h0 = hc.x, h1 = hc.y, h2 = hc.z, h3 = hc.w;

  float4 al = *(const float4*)(A_log + d * DS + s4 * 4);
  float A0 = fminf(-expf(al.x), -1e-4f);
  float A1 = fminf(-expf(al.y), -1e-4f);
  float A2 = fminf(-expf(al.z), -1e-4f);
  float A3 = fminf(-expf(al.w), -1e-4f);
  float Dd = Dv[d];

  int l0 = c * CL;
  const float* dt_p = dtw + ((size_t)b * LL + l0) * DM + d;
  const float* x_p  = x   + ((size_t)b * LL + l0) * DM + d;
  const float* B_p  = xz  + ((size_t)b * LL + l0) * KK + DTR + s4 * 4;
  const float* C_p  = B_p + DS;
  float* y_p = y + ((size_t)b * LL + l0) * DM + d;
#pragma unroll 4
  for (int l = 0; l < CL; ++l) {
    float dtv = dt_p[(size_t)l * DM];
    float xv  = x_p[(size_t)l * DM];
    float4 Bv = *(const float4*)(B_p + (size_t)l * KK);
    float4 Cv = *(const float4*)(C_p + (size_t)l * KK);
    float dtx = dtv * xv;
    float a0 = fminf(__expf(dtv * A0), 1.f);
    float a1 = fminf(__expf(dtv * A1), 1.f);
    float a2 = fminf(__expf(dtv * A2), 1.f);
    float a3 = fminf(__expf(dtv * A3), 1.f);
    h0 = fmaf(a0, h0, dtx * Bv.x);
    h1 = fmaf(a1, h1, dtx * Bv.y);
    h2 = fmaf(a2, h2, dtx * Bv.z);
    h3 = fmaf(a3, h3, dtx * Bv.w);
    float p = h0 * Cv.x;
    p = fmaf(h1, Cv.y, p);
    p = fmaf(h2, Cv.z, p);
    p = fmaf(h3, Cv.w, p);
    p += __shfl_xor(p, 1);
    p += __shfl_xor(p, 2);
    if (s4 == 0)
      y_p[(size_t)l * DM] = fmaf(xv, Dd, p);
  }
}

extern "C" void kernel_launch(void* const* d_in, const int* in_sizes, int n_in,
                              void* d_out, int out_size, void* d_ws, size_t ws_size,
                              hipStream_t stream) {
  const float* x     = (const float*)d_in[0];
  const float* W_x   = (const float*)d_in[1];
  const float* W_dt  = (const float*)d_in[2];
  const float* b_dt  = (const float*)d_in[3];
  const float* A_log = (const float*)d_in[4];
  const float* Dv    = (const float*)d_in[5];
  float* y = (float*)d_out;

  float* ws   = (float*)d_ws;
  float* WxT  = ws + OFF_WXT;
  float* WdtT = ws + OFF_WDTT;
  float* xz   = ws + OFF_XZ;
  float* dtw  = ws + OFF_DT;
  float* Pb   = ws + OFF_P;
  float* Hb   = ws + OFF_H;
  float* Cb   = ws + OFF_C;

  k_transpose<<<192, 256, 0, stream>>>(W_x, W_dt, WxT, WdtT);
  k_xz<<<NROWS / 8, 512, 0, stream>>>(x, WxT, xz);
  k_dt<<<(NROWS / 8) * 2, 256, 0, stream>>>(xz, WdtT, b_dt, dtw);
  dim3 g(NC, BB * (DM / 64));
  k_scan1<<<g, 256, 0, stream>>>(x, xz, dtw, A_log, Pb, Hb);
  k_mid<<<CHAINS / 256, 256, 0, stream>>>(Pb, Hb, Cb);
  k_scan2<<<g, 256, 0, stream>>>(x, xz, dtw, A_log, Dv, Cb, y);
}